// Round 11
// baseline (288.791 us; speedup 1.0000x reference)
//
#include <hip/hip_runtime.h>
#include <hip/hip_bf16.h>

#define WD 50
#define PD 5
#define HID 230
#define RELN 53
#define LLEN 120
#define BAGS 512
#define BB 8
#define NSENT 4096
#define QL 8
#define CIN 160     // 3*WD + 2*PD
#define KTOT 480    // 3 * CIN
#define XROW 168    // padded LDS row (bf16 elems); 336B stride = 2-way alias (floor for 16B-aligned rows)
#define XROWS 122   // rows -1..120 (l+tap); reads beyond feed only masked outputs

typedef __attribute__((ext_vector_type(4))) float f32x4;
typedef __attribute__((ext_vector_type(8))) short short8;

__device__ __forceinline__ float bf2f(short u) {
    union { float f; unsigned int i; } v;
    v.i = ((unsigned int)(unsigned short)u) << 16;
    return v.f;
}
__device__ __forceinline__ short f2bf(float f) {
    union { float f; unsigned int i; } v; v.f = f;
    unsigned int r = v.i + 0x7FFFu + ((v.i >> 16) & 1u);  // RNE
    return (short)(r >> 16);
}
// one-instruction packed f32x2 -> bf16x2, lo = a, hi = b (round-6-proven)
__device__ __forceinline__ unsigned int cvtpk(float a, float b) {
    unsigned int r;
    asm("v_cvt_pk_bf16_f32 %0, %1, %2" : "=v"(r) : "v"(a), "v"(b));
    return r;
}

// ---------------- build per-bag query q[BAGS][QL][WD] ----------------
__global__ void build_q_kernel(const int* __restrict__ Q, const int* __restrict__ E1,
                               const int* __restrict__ E2, const float* __restrict__ W_word,
                               float* __restrict__ q_ws) {
    int b = blockIdx.x;
    int d = threadIdx.x;
    if (d >= WD) return;
    float e1 = 0.5f * (W_word[E1[2 * b] * WD + d] + W_word[E1[2 * b + 1] * WD + d]);
    float e2 = 0.5f * (W_word[E2[2 * b] * WD + d] + W_word[E2[2 * b + 1] * WD + d]);
    for (int j = 0; j < QL; ++j) {
        float v;
        if (j == QL - 4)      v = e1;
        else if (j == QL - 2) v = e2;
        else                  v = W_word[Q[b * QL + j] * WD + d];
        q_ws[(b * QL + j) * WD + d] = v;
    }
}

// ---------------- pack conv weights -> wt2[15][256][32] bf16 (coalesced B-frags) ----------------
__global__ void pack_w_kernel(const float* __restrict__ conv_W, short* __restrict__ wt2) {
    int i = blockIdx.x * 256 + threadIdx.x;   // 15*256*32 = 122880
    if (i >= 15 * 256 * 32) return;
    int ks = i >> 13, rem = i & 8191;
    int row = rem >> 5, kk = rem & 31;
    int k = ks * 32 + kk;                     // global k = tap*160 + c
    float v = (row < HID) ? conv_W[k * HID + row] : 0.f;
    wt2[i] = f2bf(v);
}

// ---------------- fused per-sentence: attention (MFMA) -> x -> conv(k=3) -> max -> relu ----------------
__launch_bounds__(512, 6)
__global__ void sent_kernel(const int* __restrict__ X, const int* __restrict__ XP1,
                            const int* __restrict__ XP2,
                            const float* __restrict__ W_word,
                            const float* __restrict__ W_pos1, const float* __restrict__ W_pos2,
                            const float* __restrict__ w_s, const float* __restrict__ b_s,
                            const float* __restrict__ w_q, const float* __restrict__ b_q,
                            const float* __restrict__ w_sq, const float* __restrict__ b_sq,
                            const float* __restrict__ conv_b,
                            const float* __restrict__ q_ws, const short* __restrict__ wt2,
                            float* __restrict__ enc) {
    extern __shared__ char smem[];
    short* xl  = (short*)smem;                      // [122][168] bf16 x tile        40992B
    short* qtb = xl + XROWS * XROW;                 // [64][32] bf16 q^T              4096B
    short* abf = qtb + 64 * 32;                     // [136][8] bf16 a rows           2176B
    short* qwb = abf + 136 * 8;                     // [16][64] q*w_sq / w_s; 2056B
    float* smax = (float*)qwb;                      // [1024] f32 overlay (qwb+bat+qsv+pad, all dead by P7)
    float* red  = smax + 1024;                      // [1]
    float* bat  = (float*)((char*)qwb + 2056);      // [120] f32 unnormalized exp
    float* qsv  = bat + LLEN;                       // [8]

    const int tid = threadIdx.x;
    const int n = blockIdx.x;
    const int bag = n >> 3;
    const int lane = tid & 63;
    const int wid = tid >> 6;
    const int r16 = lane & 15;
    const int g = lane >> 4;

    // ================= P1 (single phase, one barrier): pads + gathers + small weights =========
    {
        int* xli = (int*)xl;
        // zero xl pad rows {0,121}
        for (int i = tid; i < 168; i += 512) {
            int col = (i < 84) ? i : (i - 84);
            int row = (i < 84) ? 0 : 121;
            xli[row * 84 + col] = 0;
        }
        // zero xl int-cols 25..32 (shorts 50..65) of rows 1..120: P2's K=64 A-read needs
        // cols 50..63 zero; shorts 64..65 are rewritten by P5 before the conv reads them.
        for (int i = tid; i < 960; i += 512) {
            int row = 1 + (i >> 3), ci = 25 + (i & 7);
            xli[row * 84 + ci] = 0;
        }
        // zero abf rows 120..135 (P5 stride-8 trick reads them)
        int* abfi = (int*)abf;
        if (tid < 64) abfi[120 * 4 + tid] = 0;
    }
    // gather s -> xl cols 0..49: 4 threads/row, one X-load each, float2 W loads, cvt_pk packs
    if (tid < 480) {
        int l = tid >> 2, q = tid & 3;
        const float* wr = W_word + X[n * LLEN + l] * WD;
        short* dst = xl + (l + 1) * XROW;
        int dp = q * 6;
        int dpe = dp + 6 + (q == 3 ? 1 : 0);
        for (; dp < dpe; ++dp) {
            float2 v = *(const float2*)(wr + dp * 2);
            *(unsigned int*)(dst + dp * 2) = cvtpk(v.x, v.y);
        }
    }
    // pos -> xl cols 150..159: 2 threads/row
    if (tid < 240) {
        int l = tid >> 1, hh = tid & 1;
        const int idx = (hh ? XP2 : XP1)[n * LLEN + l];
        const float* wp = (hh ? W_pos2 : W_pos1) + idx * PD;
        short* dst = xl + (l + 1) * XROW + 150 + hh * PD;
        for (int c = 0; c < PD; ++c) dst[c] = f2bf(wp[c]);
    }
    // qtb: fill row d (cols j<8) AND zero cols 8..31 / rows >=50 in the same thread
    if (tid >= 448) {
        int d = tid - 448;
        short8 v = (short8){0, 0, 0, 0, 0, 0, 0, 0};
        if (d < WD)
            for (int j = 0; j < QL; ++j) v[j] = f2bf(q_ws[(bag * QL + j) * WD + d]);
        short* dst = qtb + d * 32;
        short8 z = (short8){0, 0, 0, 0, 0, 0, 0, 0};
        *(short8*)(dst) = v;
        *(short8*)(dst + 8) = z;
        *(short8*)(dst + 16) = z;
        *(short8*)(dst + 24) = z;
    }
    // qwb rows 0..7 = q*w_sq (cols>=50 zero), row 8 = w_s
    if (tid >= 376 && tid < 448) {
        int t = tid - 376, j = t >> 3, g8 = t & 7;
        short8 v;
        for (int e = 0; e < 8; ++e) {
            int c = g8 * 8 + e;
            float x = 0.f;
            if (c < WD) x = (j < 8) ? q_ws[(bag * QL + j) * WD + c] * w_sq[c] : w_s[c];
            v[e] = f2bf(x);
        }
        *(short8*)(qwb + j * 64 + g8 * 8) = v;
    }
    // qsv[j] = q.w_q + b_q
    if (tid >= 368 && tid < 376) {
        int j = tid - 368;
        float acc = b_q[0];
        for (int d = 0; d < WD; ++d) acc += q_ws[(bag * QL + j) * WD + d] * w_q[d];
        qsv[j] = acc;
    }
    __syncthreads();

    // ====== P2: h' = s @ [qw; w_s]^T (M=128,N=16,K=64) + FUSED j-softmax via shfl ======
    {
        const float bsq = b_sq[0], bs = b_s[0];
        f32x4 hacc = (f32x4){0.f, 0.f, 0.f, 0.f};
        for (int ks2 = 0; ks2 < 2; ++ks2) {
            short8 af = *(const short8*)(xl + (1 + 16 * wid + r16) * XROW + ks2 * 32 + g * 8);
            short8 bf = *(const short8*)(qwb + r16 * 64 + ks2 * 32 + g * 8);
            hacc = __builtin_amdgcn_mfma_f32_16x16x32_bf16(af, bf, hacc, 0, 0, 0);
        }
        const float qs = (r16 < QL) ? (qsv[r16] + bsq) : 0.f;
        float an[4], mx[4];
#pragma unroll
        for (int r = 0; r < 4; ++r) {
            float h = hacc[r] + qs;
            float m = h;
            m = fmaxf(m, __shfl_xor(m, 1, 64));
            m = fmaxf(m, __shfl_xor(m, 2, 64));
            m = fmaxf(m, __shfl_xor(m, 4, 64));
            mx[r] = m;
            float a = __expf(h - m);
            float s = a;
            s += __shfl_xor(s, 1, 64);
            s += __shfl_xor(s, 2, 64);
            s += __shfl_xor(s, 4, 64);
            an[r] = a / s;
        }
        unsigned int w[4];
#pragma unroll
        for (int r = 0; r < 4; ++r) w[r] = cvtpk(an[r], __shfl_xor(an[r], 1, 64));
        if (r16 < QL && !(r16 & 1)) {       // even-j lanes write packed (j, j+1)
#pragma unroll
            for (int r = 0; r < 4; ++r) {
                int l = 16 * wid + 4 * g + r;
                if (l < LLEN) *(unsigned int*)(abf + l * 8 + r16) = w[r];
            }
        }
#pragma unroll
        for (int r = 0; r < 4; ++r) mx[r] = __shfl_xor(mx[r], 8, 64);  // lane 8 <- lane 0's max
        if (r16 == QL) {
#pragma unroll
            for (int r = 0; r < 4; ++r) {
                int l = 16 * wid + 4 * g + r;
                if (l < LLEN) bat[l] = __expf(mx[r] + hacc[r] + bs);  // logits O(1): safe
            }
        }
    }
    __syncthreads();

    // ================= P4: q2s partials + sum(bat)  (smax low region overlays dead qwb) =================
    if (tid < 400) {
        int c = tid / WD, d = tid % WD;
        float acc = 0.f;
        for (int l = c * 15; l < c * 15 + 15; ++l)
            acc += bat[l] * bf2f(xl[(l + 1) * XROW + d]);
        smax[c * 52 + d] = acc;            // smax[0..415]: inside qwb region, no bat overlap
    } else if (tid >= 448) {
        int ln = tid - 448;
        float v = (ln < LLEN ? bat[ln] : 0.f) + (ln + 64 < LLEN ? bat[ln + 64] : 0.f);
        for (int o = 32; o >= 1; o >>= 1) v += __shfl_xor(v, o, 64);
        if (ln == 0) red[0] = v;           // red at smax+1024: beyond bat/qsv, inside alloc
    }
    __syncthreads();

    // ================= P5: s2q = a @ q; write x cols 50..99 and 100..149 =================
    {
        float rinv = 1.0f / red[0];
        short8 af = *(const short8*)(abf + (16 * wid + r16) * 8 + g * 8);
        for (int nt = 0; nt < 4; ++nt) {
            short8 bf = *(const short8*)(qtb + (16 * nt + r16) * 32 + g * 8);
            f32x4 acc2 = __builtin_amdgcn_mfma_f32_16x16x32_bf16(
                af, bf, (f32x4){0.f, 0.f, 0.f, 0.f}, 0, 0, 0);
            int d = 16 * nt + r16;
            if (d < WD) {
                float q2sd = 0.f;
                for (int c = 0; c < 8; ++c) q2sd += smax[c * 52 + d];
                q2sd *= rinv;
                for (int r = 0; r < 4; ++r) {
                    int l = 16 * wid + 4 * g + r;
                    if (l < LLEN) {
                        short* row = xl + (l + 1) * XROW;
                        float s = bf2f(row[d]);
                        unsigned int pk = cvtpk(s * acc2[r], s * q2sd);
                        row[50 + d]  = (short)(pk & 0xFFFFu);
                        row[100 + d] = (short)(pk >> 16);
                    }
                }
            }
        }
    }
    __syncthreads();

    // ================= P7: conv MFMA 16x16x32 (M=128, N=256, K=480), two N-half passes =================
    // Wave grid 4wm x 2wn, mf=2, nf=4: A-LDS reads halve (960->480 b128/block) vs 2wm x 4wn;
    // B re-reads (960 dwordx4) come from L1/L2-resident wt2 (240KB). acc[2][4]=32 regs; B
    // single-buffered (r10 showed pipeline depth is a non-factor; TLP hides L2 latency).
    const int wm4 = wid >> 1;  // 0..3 -> rows 32*wm4 + 16*mf
    const int wn2 = wid & 1;   // 0..1 -> cols 64*wn2 within the 128-col pass
    const int m0 = 32 * wm4 + r16;
    const short* wbase = wt2 + (64 * wn2 + r16) * 32 + g * 8;
    const int aoff_base = m0 * XROW + g * 8;

#pragma unroll 1
    for (int p = 0; p < 2; ++p) {
        f32x4 acc[2][4];
#pragma unroll
        for (int a = 0; a < 2; ++a)
#pragma unroll
            for (int b2 = 0; b2 < 4; ++b2) acc[a][b2] = (f32x4){0.f, 0.f, 0.f, 0.f};
        const short* wb = wbase + p * 4096;   // +128 cols = 128*32 shorts
        int aoff = aoff_base;

#pragma unroll 1
        for (int ks = 0; ks < 15; ++ks) {
            const short* wk = wb + ks * 8192;
            short8 bfr[4];
#pragma unroll
            for (int nf = 0; nf < 4; ++nf) bfr[nf] = *(const short8*)(wk + nf * 512);
#pragma unroll
            for (int mf = 0; mf < 2; ++mf) {
                short8 afr = *(const short8*)(xl + aoff + mf * (16 * XROW));
#pragma unroll
                for (int nf = 0; nf < 4; ++nf)
                    acc[mf][nf] = __builtin_amdgcn_mfma_f32_16x16x32_bf16(afr, bfr[nf], acc[mf][nf], 0, 0, 0);
            }
            aoff += 32 + ((ks == 4 || ks == 9) ? 8 : 0);  // tap wraps 4->5, 9->10: +XROW-160
        }
        // epilogue pass p: max over valid l, cross-lane reduce, stage to smax[4][256]
#pragma unroll
        for (int nf = 0; nf < 4; ++nf) {
            float m = -1e30f;
#pragma unroll
            for (int mf = 0; mf < 2; ++mf) {
                int lbase = 32 * wm4 + 16 * mf + 4 * g;
#pragma unroll
                for (int r = 0; r < 4; ++r)
                    if (lbase + r < LLEN) m = fmaxf(m, acc[mf][nf][r]);
            }
            m = fmaxf(m, __shfl_xor(m, 16, 64));
            m = fmaxf(m, __shfl_xor(m, 32, 64));
            if (lane < 16) smax[wm4 * 256 + 128 * p + 64 * wn2 + 16 * nf + r16] = m;
        }
    }
    __syncthreads();
    for (int h = tid; h < HID; h += 512) {
        float v = fmaxf(fmaxf(smax[h], smax[256 + h]), fmaxf(smax[512 + h], smax[768 + h]))
                + conv_b[h];
        enc[n * HID + h] = fmaxf(v, 0.f);
    }
}

// ---------------- bag self-attention + relation scores ----------------
__global__ void bag_kernel(const float* __restrict__ enc, const int* __restrict__ X_Rel,
                           const float* __restrict__ rel_W, const float* __restrict__ rel_b,
                           float* __restrict__ out) {
    __shared__ float bagv[BB][232];
    __shared__ float bag2[BB][232];
    __shared__ float att[BB][BB];
    __shared__ float relv[232];
    __shared__ float repv[232];
    __shared__ float sc[BB], sc2[BB];
    const int b = blockIdx.x, t = threadIdx.x;

    for (int i = t; i < BB * HID; i += 256) {
        int r = i / HID, d = i % HID;
        bagv[r][d] = enc[(b * BB + r) * HID + d];
    }
    __syncthreads();
    if (t < 64) {
        int i = t >> 3, j = t & 7;
        float acc = 0.f;
        for (int d = 0; d < HID; ++d) acc += bagv[i][d] * bagv[j][d];
        att[i][j] = acc * (1.0f / sqrtf(230.0f));
    }
    __syncthreads();
    if (t < 8) {
        float m = att[t][0];
        for (int j = 1; j < 8; ++j) m = fmaxf(m, att[t][j]);
        float e[8], s = 0.f;
        for (int j = 0; j < 8; ++j) { e[j] = expf(att[t][j] - m); s += e[j]; }
        float inv = 1.f / s;
        for (int j = 0; j < 8; ++j) att[t][j] = e[j] * inv;
    }
    __syncthreads();
    for (int i = t; i < BB * HID; i += 256) {
        int r = i / HID, d = i % HID;
        float acc = 0.f;
        for (int j = 0; j < 8; ++j) acc += att[r][j] * bagv[j][d];
        bag2[r][d] = acc;
    }
    if (t < HID) relv[t] = rel_W[X_Rel[b] * HID + t];
    __syncthreads();
    if (t < 8) {
        float acc = 0.f;
        for (int d = 0; d < HID; ++d) acc += bag2[t][d] * relv[d];
        sc[t] = acc;
    }
    __syncthreads();
    if (t < 8) {
        float m = sc[0];
        for (int j = 1; j < 8; ++j) m = fmaxf(m, sc[j]);
        sc2[t] = expf(sc[t] - m);
    }
    __syncthreads();
    if (t < HID) {
        float sum = 0.f;
        for (int j = 0; j < 8; ++j) sum += sc2[j];
        float acc = 0.f;
        for (int j = 0; j < 8; ++j) acc += sc2[j] * bag2[j][t];
        repv[t] = acc / sum;
    }
    __syncthreads();
    if (t < RELN) {
        float acc = rel_b[t];
        for (int d = 0; d < HID; ++d) acc += repv[d] * rel_W[t * HID + d];
        out[b * RELN + t] = acc;
    }
}

extern "C" void kernel_launch(void* const* d_in, const int* in_sizes, int n_in,
                              void* d_out, int out_size, void* d_ws, size_t ws_size,
                              hipStream_t stream) {
    const int* X       = (const int*)d_in[0];
    const int* XP1     = (const int*)d_in[1];
    const int* XP2     = (const int*)d_in[2];
    const int* E1      = (const int*)d_in[3];
    const int* E2      = (const int*)d_in[4];
    const int* Q       = (const int*)d_in[10];
    const int* X_Rel   = (const int*)d_in[11];
    const float* W_word = (const float*)d_in[12];
    const float* W_pos1 = (const float*)d_in[13];
    const float* W_pos2 = (const float*)d_in[14];
    const float* w_s   = (const float*)d_in[15];
    const float* b_s   = (const float*)d_in[16];
    const float* w_q   = (const float*)d_in[17];
    const float* b_q   = (const float*)d_in[18];
    const float* w_sq  = (const float*)d_in[19];
    const float* b_sq  = (const float*)d_in[20];
    const float* conv_W = (const float*)d_in[21];
    const float* conv_b = (const float*)d_in[22];
    const float* rel_W = (const float*)d_in[23];
    const float* rel_b = (const float*)d_in[24];
    float* out = (float*)d_out;

    char* ws = (char*)d_ws;
    float* q_ws = (float*)ws;                      // 512*8*50 f32
    float* enc  = q_ws + BAGS * QL * WD;           // 4096*230 f32
    short* wt2  = (short*)(enc + NSENT * HID);     // 15*256*32 bf16

    build_q_kernel<<<BAGS, 64, 0, stream>>>(Q, E1, E2, W_word, q_ws);
    pack_w_kernel<<<480, 256, 0, stream>>>(conv_W, wt2);

    const size_t lds_bytes =
        (size_t)XROWS * XROW * 2      // xl     40992
        + 64 * 32 * 2                 // qtb     4096
        + 136 * 8 * 2                 // abf     2176
        + 2056                        // qwb
        + 4 * LLEN                    // bat      480
        + 4 * QL                      // qsv       32
        + 1536;                       // smax[1024]+red overlay tail pad -> total 51368 (3 blocks/CU)
    sent_kernel<<<NSENT, 512, lds_bytes, stream>>>(
        X, XP1, XP2, W_word, W_pos1, W_pos2,
        w_s, b_s, w_q, b_q, w_sq, b_sq, conv_b, q_ws, wt2, enc);

    bag_kernel<<<BAGS, 256, 0, stream>>>(enc, X_Rel, rel_W, rel_b, out);
}

// Round 12
// 194.911 us; speedup vs baseline: 1.4817x; 1.4817x over previous
//
#include <hip/hip_runtime.h>
#include <hip/hip_bf16.h>

#define WD 50
#define PD 5
#define HID 230
#define RELN 53
#define LLEN 120
#define BAGS 512
#define BB 8
#define NSENT 4096
#define QL 8
#define CIN 160     // 3*WD + 2*PD
#define KTOT 480    // 3 * CIN
#define XROW 168    // padded LDS row (bf16 elems); 336B stride
#define XROWS 122   // rows -1..120 (l+tap); reads beyond feed only masked outputs

typedef __attribute__((ext_vector_type(4))) float f32x4;
typedef __attribute__((ext_vector_type(8))) short short8;

__device__ __forceinline__ float bf2f(short u) {
    union { float f; unsigned int i; } v;
    v.i = ((unsigned int)(unsigned short)u) << 16;
    return v.f;
}
__device__ __forceinline__ short f2bf(float f) {
    union { float f; unsigned int i; } v; v.f = f;
    unsigned int r = v.i + 0x7FFFu + ((v.i >> 16) & 1u);  // RNE
    return (short)(r >> 16);
}

// ---------------- build per-bag query q[BAGS][QL][WD] ----------------
__global__ void build_q_kernel(const int* __restrict__ Q, const int* __restrict__ E1,
                               const int* __restrict__ E2, const float* __restrict__ W_word,
                               float* __restrict__ q_ws) {
    int b = blockIdx.x;
    int d = threadIdx.x;
    if (d >= WD) return;
    float e1 = 0.5f * (W_word[E1[2 * b] * WD + d] + W_word[E1[2 * b + 1] * WD + d]);
    float e2 = 0.5f * (W_word[E2[2 * b] * WD + d] + W_word[E2[2 * b + 1] * WD + d]);
    for (int j = 0; j < QL; ++j) {
        float v;
        if (j == QL - 4)      v = e1;
        else if (j == QL - 2) v = e2;
        else                  v = W_word[Q[b * QL + j] * WD + d];
        q_ws[(b * QL + j) * WD + d] = v;
    }
}

// ---------------- pack conv weights -> wt2[15][256][32] bf16 (coalesced B-frags) ----------------
__global__ void pack_w_kernel(const float* __restrict__ conv_W, short* __restrict__ wt2) {
    int i = blockIdx.x * 256 + threadIdx.x;   // 15*256*32 = 122880
    if (i >= 15 * 256 * 32) return;
    int ks = i >> 13, rem = i & 8191;
    int row = rem >> 5, kk = rem & 31;
    int k = ks * 32 + kk;                     // global k = tap*160 + c
    float v = (row < HID) ? conv_W[k * HID + row] : 0.f;
    wt2[i] = f2bf(v);
}

// ---------------- fused per-sentence: attention (MFMA) -> x -> conv(k=3) -> max -> relu ----------------
__launch_bounds__(512, 6)
__global__ void sent_kernel(const int* __restrict__ X, const int* __restrict__ XP1,
                            const int* __restrict__ XP2,
                            const float* __restrict__ W_word,
                            const float* __restrict__ W_pos1, const float* __restrict__ W_pos2,
                            const float* __restrict__ w_s, const float* __restrict__ b_s,
                            const float* __restrict__ w_q, const float* __restrict__ b_q,
                            const float* __restrict__ w_sq, const float* __restrict__ b_sq,
                            const float* __restrict__ conv_b,
                            const float* __restrict__ q_ws, const short* __restrict__ wt2,
                            float* __restrict__ enc) {
    extern __shared__ char smem[];
    short* xl  = (short*)smem;                       // [122][168] bf16 x tile
    short* qtb = xl + XROWS * XROW;                  // [64][32] bf16 q^T (row d, col j)
    short* abf = qtb + 64 * 32;                      // [136][8] bf16 a rows (A-garbage x B-zero = 0 trick)
    short* qwb = abf + 136 * 8;                      // [16][64] bf16: rows 0-7 q*w_sq, row 8 w_s
    short* hm  = qwb + 16 * 64;                      // [120][8] bf16 h' rows
    float* svv = (float*)(hm + LLEN * 8);            // [120] s.w_s + b_s
    float* bat = svv + LLEN;                         // [120] unnormalized exp
    float* qsv = bat + LLEN;                         // [8]
    float* smax = (float*)qwb;                       // [512]+[1] overlay on qwb+hm (dead after P3)
    float* red  = smax + 512;

    const int tid = threadIdx.x;
    const int n = blockIdx.x;
    const int bag = n >> 3;
    const int lane = tid & 63;
    const int wid = tid >> 6;
    const int r16 = lane & 15;
    const int g = lane >> 4;

    // ================= P1: zero pads + gather + small weights =================
    {
        int* xli = (int*)xl;
        // zero xl pad rows {0,121}
        for (int i = tid; i < 168; i += 512) {
            int col = (i < 84) ? i : (i - 84);
            int row = (i < 84) ? 0 : 121;
            xli[row * 84 + col] = 0;
        }
        // zero xl int-cols 25..32 (shorts 50..65) of rows 1..120 (read by P2 K=64)
        for (int i = tid; i < 960; i += 512) {
            int row = 1 + (i >> 3), ci = 25 + (i & 7);
            xli[row * 84 + ci] = 0;
        }
        // zero abf rows 120..135 (P5 stride-8 trick reads them; B-zero covers k>=8)
        int* abfi = (int*)abf;
        if (tid < 64) abfi[120 * 4 + tid] = 0;
        // zero qtb (cols >=8 and rows >=50 must be 0)
        int* qtbi = (int*)qtb;
        for (int i = tid; i < 1024; i += 512) qtbi[i] = 0;
    }
    // gather s -> xl cols 0..49: 4 threads/row, ONE X-load each, float2 W loads, div-free
    if (tid < 480) {
        int l = tid >> 2, q = tid & 3;
        const float* wr = W_word + X[n * LLEN + l] * WD;
        short* dst = xl + (l + 1) * XROW;
        int dp = q * 6;
        int dpe = dp + 6 + (q == 3 ? 1 : 0);
        for (; dp < dpe; ++dp) {
            float2 v = *(const float2*)(wr + dp * 2);
            unsigned int pk = ((unsigned int)(unsigned short)f2bf(v.y) << 16)
                            | (unsigned short)f2bf(v.x);
            *(unsigned int*)(dst + dp * 2) = pk;
        }
    }
    // pos -> xl cols 150..159: 2 threads/row, div-free
    if (tid < 240) {
        int l = tid >> 1, hh = tid & 1;
        const int idx = (hh ? XP2 : XP1)[n * LLEN + l];
        const float* wp = (hh ? W_pos2 : W_pos1) + idx * PD;
        short* dst = xl + (l + 1) * XROW + 150 + hh * PD;
        for (int c = 0; c < PD; ++c) dst[c] = f2bf(wp[c]);
    }
    __syncthreads();   // qtb zero must precede qtb fill
    // qtb rows d<50: col j<8 = q[j][d]
    if (tid < WD) {
        short8 v;
        for (int j = 0; j < QL; ++j) v[j] = f2bf(q_ws[(bag * QL + j) * WD + tid]);
        *(short8*)(qtb + tid * 32) = v;
    }
    // qwb rows 0..7 = q*w_sq (cols>=50 zero), row 8 = w_s
    if (tid >= 64 && tid < 64 + 72) {
        int t = tid - 64, j = t >> 3, g8 = t & 7;
        short8 v;
        for (int e = 0; e < 8; ++e) {
            int c = g8 * 8 + e;
            float x = 0.f;
            if (c < WD) x = (j < 8) ? q_ws[(bag * QL + j) * WD + c] * w_sq[c] : w_s[c];
            v[e] = f2bf(x);
        }
        *(short8*)(qwb + j * 64 + g8 * 8) = v;
    }
    // qsv[j] = q.w_q + b_q
    if (tid >= 504) {
        int j = tid - 504;
        float acc = b_q[0];
        for (int d = 0; d < WD; ++d) acc += q_ws[(bag * QL + j) * WD + d] * w_q[d];
        qsv[j] = acc;
    }
    __syncthreads();

    // ================= P2: h' = s @ [qw; w_s]^T  (M=128, N=16, K=64) =================
    {
        const float bsq = b_sq[0], bs = b_s[0];
        f32x4 hacc = (f32x4){0.f, 0.f, 0.f, 0.f};
        for (int ks2 = 0; ks2 < 2; ++ks2) {
            short8 af = *(const short8*)(xl + (1 + 16 * wid + r16) * XROW + ks2 * 32 + g * 8);
            short8 bf = *(const short8*)(qwb + r16 * 64 + ks2 * 32 + g * 8);
            hacc = __builtin_amdgcn_mfma_f32_16x16x32_bf16(af, bf, hacc, 0, 0, 0);
        }
        if (r16 < QL) {
            float qs = qsv[r16] + bsq;
            for (int r = 0; r < 4; ++r) {
                int l = 16 * wid + 4 * g + r;
                if (l < LLEN) hm[l * 8 + r16] = f2bf(hacc[r] + qs);
            }
        } else if (r16 == QL) {
            for (int r = 0; r < 4; ++r) {
                int l = 16 * wid + 4 * g + r;
                if (l < LLEN) svv[l] = hacc[r] + bs;
            }
        }
    }
    __syncthreads();

    // ================= P3: softmax over j -> abf; bat = exp(rowmax + sv) =================
    if (tid < LLEN) {
        const int l = tid;
        short8 hrow = *(const short8*)(hm + l * 8);
        float a[8], m = -1e30f;
        for (int j = 0; j < 8; ++j) { a[j] = bf2f(hrow[j]); m = fmaxf(m, a[j]); }
        float sum = 0.f;
        for (int j = 0; j < 8; ++j) { a[j] = expf(a[j] - m); sum += a[j]; }
        float inv = 1.f / sum;
        short8 arow;
        for (int j = 0; j < 8; ++j) arow[j] = f2bf(a[j] * inv);
        *(short8*)(abf + l * 8) = arow;
        bat[l] = expf(m + svv[l]);   // logits are O(1): safe without max-subtraction
    }
    __syncthreads();

    // ================= P4: q2s partials + sum(bat)  (smax overlays dead qwb/hm) =================
    if (tid < 400) {
        int c = tid / WD, d = tid % WD;
        float acc = 0.f;
        for (int l = c * 15; l < c * 15 + 15; ++l)
            acc += bat[l] * bf2f(xl[(l + 1) * XROW + d]);
        smax[c * 52 + d] = acc;
    } else if (tid >= 448) {
        int ln = tid - 448;
        float v = (ln < LLEN ? bat[ln] : 0.f) + (ln + 64 < LLEN ? bat[ln + 64] : 0.f);
        for (int o = 32; o >= 1; o >>= 1) v += __shfl_xor(v, o, 64);
        if (ln == 0) red[0] = v;
    }
    __syncthreads();

    // ================= P5: s2q = a @ q; write x cols 50..99 and 100..149 =================
    {
        float rinv = 1.0f / red[0];
        short8 af = *(const short8*)(abf + (16 * wid + r16) * 8 + g * 8);
        for (int nt = 0; nt < 4; ++nt) {
            short8 bf = *(const short8*)(qtb + (16 * nt + r16) * 32 + g * 8);
            f32x4 acc2 = __builtin_amdgcn_mfma_f32_16x16x32_bf16(
                af, bf, (f32x4){0.f, 0.f, 0.f, 0.f}, 0, 0, 0);
            int d = 16 * nt + r16;
            if (d < WD) {
                float q2sd = 0.f;
                for (int c = 0; c < 8; ++c) q2sd += smax[c * 52 + d];
                q2sd *= rinv;
                for (int r = 0; r < 4; ++r) {
                    int l = 16 * wid + 4 * g + r;
                    if (l < LLEN) {
                        short* row = xl + (l + 1) * XROW;
                        float s = bf2f(row[d]);
                        row[50 + d]  = f2bf(s * acc2[r]);
                        row[100 + d] = f2bf(s * q2sd);
                    }
                }
            }
        }
    }
    __syncthreads();

    // ================= P7: conv MFMA 16x16x32 (M=128, N=240 effective, K=480) =================
    // Round-8 structure (best measured) + skip of the all-zero tile cols 240..255
    // (p=1, wn=3, nf=1): -6.25% MFMA, -6% B-loads. en1 is wave-uniform; afr[4]-hoisted
    // half-groups keep it to 2 branches per 2-ks iteration. acc32+b0/b1 16+afr16+addr ~76 regs.
    const int wm = wid >> 2;   // 0..1
    const int wn = wid & 3;    // 0..3
    const int m0 = 64 * wm + r16;
    const short* wbase = wt2 + (64 * wn + r16) * 32 + g * 8;
    const int aoff_base = m0 * XROW + g * 8;

#pragma unroll 1
    for (int p = 0; p < 2; ++p) {
        const bool en1 = !(p == 1 && wn == 3);   // nf=1 tile = cols 240..255 (all pad) when false
        f32x4 acc[4][2];
        for (int a = 0; a < 4; ++a) {
            acc[a][0] = (f32x4){0.f, 0.f, 0.f, 0.f};
            acc[a][1] = (f32x4){0.f, 0.f, 0.f, 0.f};
        }
        const short* wb = wbase + p * 1024;   // +32 cols = +32 rows * 32
        short8 b0[2], b1[2];
        b0[0] = *(const short8*)(wb);
        if (en1) b0[1] = *(const short8*)(wb + 512);
        int aoff = aoff_base;

#pragma unroll 1
        for (int ks = 0; ks < 14; ks += 2) {
            const short* wk = wb + ks * 8192;
            b1[0] = *(const short8*)(wk + 8192);
            if (en1) b1[1] = *(const short8*)(wk + 8192 + 512);
            {
                short8 afr[4];
#pragma unroll
                for (int mf = 0; mf < 4; ++mf) {
                    afr[mf] = *(const short8*)(xl + aoff + mf * (16 * XROW));
                    acc[mf][0] = __builtin_amdgcn_mfma_f32_16x16x32_bf16(afr[mf], b0[0], acc[mf][0], 0, 0, 0);
                }
                if (en1) {
#pragma unroll
                    for (int mf = 0; mf < 4; ++mf)
                        acc[mf][1] = __builtin_amdgcn_mfma_f32_16x16x32_bf16(afr[mf], b0[1], acc[mf][1], 0, 0, 0);
                }
            }
            b0[0] = *(const short8*)(wk + 16384);
            if (en1) b0[1] = *(const short8*)(wk + 16384 + 512);
            {
                const int aoff1 = aoff + ((ks == 4) ? 40 : 32);  // tap wrap 4->5 inside pair
                short8 afr[4];
#pragma unroll
                for (int mf = 0; mf < 4; ++mf) {
                    afr[mf] = *(const short8*)(xl + aoff1 + mf * (16 * XROW));
                    acc[mf][0] = __builtin_amdgcn_mfma_f32_16x16x32_bf16(afr[mf], b1[0], acc[mf][0], 0, 0, 0);
                }
                if (en1) {
#pragma unroll
                    for (int mf = 0; mf < 4; ++mf)
                        acc[mf][1] = __builtin_amdgcn_mfma_f32_16x16x32_bf16(afr[mf], b1[1], acc[mf][1], 0, 0, 0);
                }
            }
            aoff += 64 + ((ks == 4 || ks == 8) ? 8 : 0);  // wraps 4->5 and 9->10
        }
        {   // tail ks=14 (in b0)
            short8 afr[4];
#pragma unroll
            for (int mf = 0; mf < 4; ++mf) {
                afr[mf] = *(const short8*)(xl + aoff + mf * (16 * XROW));
                acc[mf][0] = __builtin_amdgcn_mfma_f32_16x16x32_bf16(afr[mf], b0[0], acc[mf][0], 0, 0, 0);
            }
            if (en1) {
#pragma unroll
                for (int mf = 0; mf < 4; ++mf)
                    acc[mf][1] = __builtin_amdgcn_mfma_f32_16x16x32_bf16(afr[mf], b0[1], acc[mf][1], 0, 0, 0);
            }
        }
        // epilogue pass p: max over valid l, cross-lane reduce, stage to smax
        // (skipped tile leaves acc[*][1]=0 -> smax cols 240..255 / 496..511, never read: h<230)
#pragma unroll
        for (int nf = 0; nf < 2; ++nf) {
            float m = -1e30f;
#pragma unroll
            for (int mf = 0; mf < 4; ++mf) {
                int lbase = 64 * wm + 16 * mf + 4 * g;
#pragma unroll
                for (int r = 0; r < 4; ++r)
                    if (lbase + r < LLEN) m = fmaxf(m, acc[mf][nf][r]);
            }
            m = fmaxf(m, __shfl_xor(m, 16, 64));
            m = fmaxf(m, __shfl_xor(m, 32, 64));
            if (lane < 16) smax[wm * 256 + 64 * wn + 32 * p + 16 * nf + r16] = m;
        }
    }
    __syncthreads();
    for (int h = tid; h < HID; h += 512) {
        float v = fmaxf(smax[h], smax[256 + h]) + conv_b[h];
        enc[n * HID + h] = fmaxf(v, 0.f);
    }
}

// ---------------- bag self-attention + relation scores ----------------
__global__ void bag_kernel(const float* __restrict__ enc, const int* __restrict__ X_Rel,
                           const float* __restrict__ rel_W, const float* __restrict__ rel_b,
                           float* __restrict__ out) {
    __shared__ float bagv[BB][232];
    __shared__ float bag2[BB][232];
    __shared__ float att[BB][BB];
    __shared__ float relv[232];
    __shared__ float repv[232];
    __shared__ float sc[BB], sc2[BB];
    const int b = blockIdx.x, t = threadIdx.x;

    for (int i = t; i < BB * HID; i += 256) {
        int r = i / HID, d = i % HID;
        bagv[r][d] = enc[(b * BB + r) * HID + d];
    }
    __syncthreads();
    if (t < 64) {
        int i = t >> 3, j = t & 7;
        float acc = 0.f;
        for (int d = 0; d < HID; ++d) acc += bagv[i][d] * bagv[j][d];
        att[i][j] = acc * (1.0f / sqrtf(230.0f));
    }
    __syncthreads();
    if (t < 8) {
        float m = att[t][0];
        for (int j = 1; j < 8; ++j) m = fmaxf(m, att[t][j]);
        float e[8], s = 0.f;
        for (int j = 0; j < 8; ++j) { e[j] = expf(att[t][j] - m); s += e[j]; }
        float inv = 1.f / s;
        for (int j = 0; j < 8; ++j) att[t][j] = e[j] * inv;
    }
    __syncthreads();
    for (int i = t; i < BB * HID; i += 256) {
        int r = i / HID, d = i % HID;
        float acc = 0.f;
        for (int j = 0; j < 8; ++j) acc += att[r][j] * bagv[j][d];
        bag2[r][d] = acc;
    }
    if (t < HID) relv[t] = rel_W[X_Rel[b] * HID + t];
    __syncthreads();
    if (t < 8) {
        float acc = 0.f;
        for (int d = 0; d < HID; ++d) acc += bag2[t][d] * relv[d];
        sc[t] = acc;
    }
    __syncthreads();
    if (t < 8) {
        float m = sc[0];
        for (int j = 1; j < 8; ++j) m = fmaxf(m, sc[j]);
        sc2[t] = expf(sc[t] - m);
    }
    __syncthreads();
    if (t < HID) {
        float sum = 0.f;
        for (int j = 0; j < 8; ++j) sum += sc2[j];
        float acc = 0.f;
        for (int j = 0; j < 8; ++j) acc += sc2[j] * bag2[j][t];
        repv[t] = acc / sum;
    }
    __syncthreads();
    if (t < RELN) {
        float acc = rel_b[t];
        for (int d = 0; d < HID; ++d) acc += repv[d] * rel_W[t * HID + d];
        out[b * RELN + t] = acc;
    }
}

extern "C" void kernel_launch(void* const* d_in, const int* in_sizes, int n_in,
                              void* d_out, int out_size, void* d_ws, size_t ws_size,
                              hipStream_t stream) {
    const int* X       = (const int*)d_in[0];
    const int* XP1     = (const int*)d_in[1];
    const int* XP2     = (const int*)d_in[2];
    const int* E1      = (const int*)d_in[3];
    const int* E2      = (const int*)d_in[4];
    const int* Q       = (const int*)d_in[10];
    const int* X_Rel   = (const int*)d_in[11];
    const float* W_word = (const float*)d_in[12];
    const float* W_pos1 = (const float*)d_in[13];
    const float* W_pos2 = (const float*)d_in[14];
    const float* w_s   = (const float*)d_in[15];
    const float* b_s   = (const float*)d_in[16];
    const float* w_q   = (const float*)d_in[17];
    const float* b_q   = (const float*)d_in[18];
    const float* w_sq  = (const float*)d_in[19];
    const float* b_sq  = (const float*)d_in[20];
    const float* conv_W = (const float*)d_in[21];
    const float* conv_b = (const float*)d_in[22];
    const float* rel_W = (const float*)d_in[23];
    const float* rel_b = (const float*)d_in[24];
    float* out = (float*)d_out;

    char* ws = (char*)d_ws;
    float* q_ws = (float*)ws;                      // 512*8*50 f32
    float* enc  = q_ws + BAGS * QL * WD;           // 4096*230 f32
    short* wt2  = (short*)(enc + NSENT * HID);     // 15*256*32 bf16

    build_q_kernel<<<BAGS, 64, 0, stream>>>(Q, E1, E2, W_word, q_ws);
    pack_w_kernel<<<480, 256, 0, stream>>>(conv_W, wt2);

    const size_t lds_bytes =
        (size_t)XROWS * XROW * 2      // xl     40992
        + 64 * 32 * 2                 // qtb     4096
        + 136 * 8 * 2                 // abf     2176
        + 16 * 64 * 2                 // qwb     2048 (smax overlay)
        + LLEN * 8 * 2                // hm      1920 (smax/red overlay tail)
        + 4 * (LLEN + LLEN + 8);      // svv/bat/qsv = 992   -> total 52224
    sent_kernel<<<NSENT, 512, lds_bytes, stream>>>(
        X, XP1, XP2, W_word, W_pos1, W_pos2,
        w_s, b_s, w_q, b_q, w_sq, b_sq, conv_b, q_ws, wt2, enc);

    bag_kernel<<<BAGS, 256, 0, stream>>>(enc, X_Rel, rel_W, rel_b, out);
}

// Round 13
// 194.723 us; speedup vs baseline: 1.4831x; 1.0010x over previous
//
#include <hip/hip_runtime.h>
#include <hip/hip_bf16.h>

#define WD 50
#define PD 5
#define HID 230
#define RELN 53
#define LLEN 120
#define BAGS 512
#define BB 8
#define NSENT 4096
#define QL 8
#define CIN 160     // 3*WD + 2*PD
#define KTOT 480    // 3 * CIN
#define XROW 168    // padded LDS row (bf16 elems); 336B stride
#define XROWS 122   // rows -1..120 (l+tap); reads beyond feed only masked outputs

typedef __attribute__((ext_vector_type(4))) float f32x4;
typedef __attribute__((ext_vector_type(8))) short short8;

__device__ __forceinline__ float bf2f(short u) {
    union { float f; unsigned int i; } v;
    v.i = ((unsigned int)(unsigned short)u) << 16;
    return v.f;
}
__device__ __forceinline__ short f2bf(float f) {
    union { float f; unsigned int i; } v; v.f = f;
    unsigned int r = v.i + 0x7FFFu + ((v.i >> 16) & 1u);  // RNE
    return (short)(r >> 16);
}

// ---------------- build per-bag query q[BAGS][QL][WD] ----------------
__global__ void build_q_kernel(const int* __restrict__ Q, const int* __restrict__ E1,
                               const int* __restrict__ E2, const float* __restrict__ W_word,
                               float* __restrict__ q_ws) {
    int b = blockIdx.x;
    int d = threadIdx.x;
    if (d >= WD) return;
    float e1 = 0.5f * (W_word[E1[2 * b] * WD + d] + W_word[E1[2 * b + 1] * WD + d]);
    float e2 = 0.5f * (W_word[E2[2 * b] * WD + d] + W_word[E2[2 * b + 1] * WD + d]);
    for (int j = 0; j < QL; ++j) {
        float v;
        if (j == QL - 4)      v = e1;
        else if (j == QL - 2) v = e2;
        else                  v = W_word[Q[b * QL + j] * WD + d];
        q_ws[(b * QL + j) * WD + d] = v;
    }
}

// ---------------- pack conv weights -> wt2[15][256][32] bf16 (coalesced B-frags) ----------------
__global__ void pack_w_kernel(const float* __restrict__ conv_W, short* __restrict__ wt2) {
    int i = blockIdx.x * 256 + threadIdx.x;   // 15*256*32 = 122880
    if (i >= 15 * 256 * 32) return;
    int ks = i >> 13, rem = i & 8191;
    int row = rem >> 5, kk = rem & 31;
    int k = ks * 32 + kk;                     // global k = tap*160 + c
    float v = (row < HID) ? conv_W[k * HID + row] : 0.f;
    wt2[i] = f2bf(v);
}

// ---------------- fused per-sentence: attention (MFMA) -> x -> conv(k=3) -> max -> relu ----------------
__launch_bounds__(512, 6)
__global__ void sent_kernel(const int* __restrict__ X, const int* __restrict__ XP1,
                            const int* __restrict__ XP2,
                            const float* __restrict__ W_word,
                            const float* __restrict__ W_pos1, const float* __restrict__ W_pos2,
                            const float* __restrict__ w_s, const float* __restrict__ b_s,
                            const float* __restrict__ w_q, const float* __restrict__ b_q,
                            const float* __restrict__ w_sq, const float* __restrict__ b_sq,
                            const float* __restrict__ conv_b,
                            const float* __restrict__ q_ws, const short* __restrict__ wt2,
                            float* __restrict__ enc) {
    extern __shared__ char smem[];
    short* xl  = (short*)smem;                       // [122][168] bf16 x tile
    short* qtb = xl + XROWS * XROW;                  // [64][32] bf16 q^T (row d, col j)
    short* abf = qtb + 64 * 32;                      // [136][8] bf16 a rows (A-garbage x B-zero = 0 trick)
    short* qwb = abf + 136 * 8;                      // [16][64] bf16: rows 0-7 q*w_sq, row 8 w_s
    short* hm  = qwb + 16 * 64;                      // [120][8] bf16 h' rows
    float* svv = (float*)(hm + LLEN * 8);            // [120] s.w_s + b_s
    float* bat = svv + LLEN;                         // [120] unnormalized exp
    float* qsv = bat + LLEN;                         // [8]
    float* smax = (float*)qwb;                       // [512]+[1] overlay on qwb+hm (dead after P3)
    float* red  = smax + 512;

    const int tid = threadIdx.x;
    const int n = blockIdx.x;
    const int bag = n >> 3;
    const int lane = tid & 63;
    const int wid = tid >> 6;
    const int r16 = lane & 15;
    const int g = lane >> 4;

    // ================= P1: zero pads + gather + small weights =================
    {
        int* xli = (int*)xl;
        // zero xl pad rows {0,121}
        for (int i = tid; i < 168; i += 512) {
            int col = (i < 84) ? i : (i - 84);
            int row = (i < 84) ? 0 : 121;
            xli[row * 84 + col] = 0;
        }
        // zero xl int-cols 25..32 (shorts 50..65) of rows 1..120 (read by P2 K=64)
        for (int i = tid; i < 960; i += 512) {
            int row = 1 + (i >> 3), ci = 25 + (i & 7);
            xli[row * 84 + ci] = 0;
        }
        // zero abf rows 120..135 (P5 stride-8 trick reads them; B-zero covers k>=8)
        int* abfi = (int*)abf;
        if (tid < 64) abfi[120 * 4 + tid] = 0;
        // zero qtb (cols >=8 and rows >=50 must be 0)
        int* qtbi = (int*)qtb;
        for (int i = tid; i < 1024; i += 512) qtbi[i] = 0;
    }
    // gather s -> xl cols 0..49: 4 threads/row, ONE X-load each, float2 W loads, div-free
    if (tid < 480) {
        int l = tid >> 2, q = tid & 3;
        const float* wr = W_word + X[n * LLEN + l] * WD;
        short* dst = xl + (l + 1) * XROW;
        int dp = q * 6;
        int dpe = dp + 6 + (q == 3 ? 1 : 0);
        for (; dp < dpe; ++dp) {
            float2 v = *(const float2*)(wr + dp * 2);
            unsigned int pk = ((unsigned int)(unsigned short)f2bf(v.y) << 16)
                            | (unsigned short)f2bf(v.x);
            *(unsigned int*)(dst + dp * 2) = pk;
        }
    }
    // pos -> xl cols 150..159: 2 threads/row, div-free
    if (tid < 240) {
        int l = tid >> 1, hh = tid & 1;
        const int idx = (hh ? XP2 : XP1)[n * LLEN + l];
        const float* wp = (hh ? W_pos2 : W_pos1) + idx * PD;
        short* dst = xl + (l + 1) * XROW + 150 + hh * PD;
        for (int c = 0; c < PD; ++c) dst[c] = f2bf(wp[c]);
    }
    __syncthreads();   // qtb zero must precede qtb fill
    // qtb rows d<50: col j<8 = q[j][d]
    if (tid < WD) {
        short8 v;
        for (int j = 0; j < QL; ++j) v[j] = f2bf(q_ws[(bag * QL + j) * WD + tid]);
        *(short8*)(qtb + tid * 32) = v;
    }
    // qwb rows 0..7 = q*w_sq (cols>=50 zero), row 8 = w_s
    if (tid >= 64 && tid < 64 + 72) {
        int t = tid - 64, j = t >> 3, g8 = t & 7;
        short8 v;
        for (int e = 0; e < 8; ++e) {
            int c = g8 * 8 + e;
            float x = 0.f;
            if (c < WD) x = (j < 8) ? q_ws[(bag * QL + j) * WD + c] * w_sq[c] : w_s[c];
            v[e] = f2bf(x);
        }
        *(short8*)(qwb + j * 64 + g8 * 8) = v;
    }
    // qsv[j] = q.w_q + b_q
    if (tid >= 504) {
        int j = tid - 504;
        float acc = b_q[0];
        for (int d = 0; d < WD; ++d) acc += q_ws[(bag * QL + j) * WD + d] * w_q[d];
        qsv[j] = acc;
    }
    __syncthreads();

    // ================= P2: h' = s @ [qw; w_s]^T  (M=128, N=16, K=64) =================
    {
        const float bsq = b_sq[0], bs = b_s[0];
        f32x4 hacc = (f32x4){0.f, 0.f, 0.f, 0.f};
        for (int ks2 = 0; ks2 < 2; ++ks2) {
            short8 af = *(const short8*)(xl + (1 + 16 * wid + r16) * XROW + ks2 * 32 + g * 8);
            short8 bf = *(const short8*)(qwb + r16 * 64 + ks2 * 32 + g * 8);
            hacc = __builtin_amdgcn_mfma_f32_16x16x32_bf16(af, bf, hacc, 0, 0, 0);
        }
        if (r16 < QL) {
            float qs = qsv[r16] + bsq;
            for (int r = 0; r < 4; ++r) {
                int l = 16 * wid + 4 * g + r;
                if (l < LLEN) hm[l * 8 + r16] = f2bf(hacc[r] + qs);
            }
        } else if (r16 == QL) {
            for (int r = 0; r < 4; ++r) {
                int l = 16 * wid + 4 * g + r;
                if (l < LLEN) svv[l] = hacc[r] + bs;
            }
        }
    }
    __syncthreads();

    // ================= P3: softmax over j -> abf; bat = exp(rowmax + sv) =================
    if (tid < LLEN) {
        const int l = tid;
        short8 hrow = *(const short8*)(hm + l * 8);
        float a[8], m = -1e30f;
        for (int j = 0; j < 8; ++j) { a[j] = bf2f(hrow[j]); m = fmaxf(m, a[j]); }
        float sum = 0.f;
        for (int j = 0; j < 8; ++j) { a[j] = expf(a[j] - m); sum += a[j]; }
        float inv = 1.f / sum;
        short8 arow;
        for (int j = 0; j < 8; ++j) arow[j] = f2bf(a[j] * inv);
        *(short8*)(abf + l * 8) = arow;
        bat[l] = expf(m + svv[l]);   // logits are O(1): safe without max-subtraction
    }
    __syncthreads();

    // ================= P4: q2s partials (vectorized b64) + sum(bat) =================
    // 104 threads x 15 short4-reads replace 400 x 15 scalar u16 (plus bat re-reads):
    // ~12000 -> ~3100 LDS ops. Quads cover d=0..51; cols 50/51 are the zeroed strip ->
    // products 0; smax slots c*52+50/51 written but never read (P5 uses d<50).
    if (tid < 128) {
        int c = tid >> 4, dq = tid & 15;        // c: l-group of 15; dq: d-quad
        if (dq < 13) {
            float s0 = 0.f, s1 = 0.f, s2 = 0.f, s3 = 0.f;
            for (int l = c * 15; l < c * 15 + 15; ++l) {
                uint2 v = *(const uint2*)(xl + (l + 1) * XROW + dq * 4);
                float b = bat[l];
                s0 += b * bf2f((short)(v.x & 0xFFFFu));
                s1 += b * bf2f((short)(v.x >> 16));
                s2 += b * bf2f((short)(v.y & 0xFFFFu));
                s3 += b * bf2f((short)(v.y >> 16));
            }
            float* dst = smax + c * 52 + dq * 4;
            dst[0] = s0; dst[1] = s1; dst[2] = s2; dst[3] = s3;
        }
    } else if (tid >= 448) {
        int ln = tid - 448;
        float v = (ln < LLEN ? bat[ln] : 0.f) + (ln + 64 < LLEN ? bat[ln + 64] : 0.f);
        for (int o = 32; o >= 1; o >>= 1) v += __shfl_xor(v, o, 64);
        if (ln == 0) red[0] = v;
    }
    __syncthreads();

    // ================= P5: s2q = a @ q; write x cols 50..99 and 100..149 =================
    {
        float rinv = 1.0f / red[0];
        short8 af = *(const short8*)(abf + (16 * wid + r16) * 8 + g * 8);
        for (int nt = 0; nt < 4; ++nt) {
            short8 bf = *(const short8*)(qtb + (16 * nt + r16) * 32 + g * 8);
            f32x4 acc2 = __builtin_amdgcn_mfma_f32_16x16x32_bf16(
                af, bf, (f32x4){0.f, 0.f, 0.f, 0.f}, 0, 0, 0);
            int d = 16 * nt + r16;
            if (d < WD) {
                float q2sd = 0.f;
                for (int c = 0; c < 8; ++c) q2sd += smax[c * 52 + d];
                q2sd *= rinv;
                for (int r = 0; r < 4; ++r) {
                    int l = 16 * wid + 4 * g + r;
                    if (l < LLEN) {
                        short* row = xl + (l + 1) * XROW;
                        float s = bf2f(row[d]);
                        row[50 + d]  = f2bf(s * acc2[r]);
                        row[100 + d] = f2bf(s * q2sd);
                    }
                }
            }
        }
    }
    __syncthreads();

    // ================= P7: conv MFMA 16x16x32 (M=128, N=240 effective, K=480) =================
    // Round-8 structure + skip of the all-zero tile cols 240..255 (p=1, wn=3, nf=1).
    const int wm = wid >> 2;   // 0..1
    const int wn = wid & 3;    // 0..3
    const int m0 = 64 * wm + r16;
    const short* wbase = wt2 + (64 * wn + r16) * 32 + g * 8;
    const int aoff_base = m0 * XROW + g * 8;

#pragma unroll 1
    for (int p = 0; p < 2; ++p) {
        const bool en1 = !(p == 1 && wn == 3);   // nf=1 tile = cols 240..255 (all pad) when false
        f32x4 acc[4][2];
        for (int a = 0; a < 4; ++a) {
            acc[a][0] = (f32x4){0.f, 0.f, 0.f, 0.f};
            acc[a][1] = (f32x4){0.f, 0.f, 0.f, 0.f};
        }
        const short* wb = wbase + p * 1024;   // +32 cols = +32 rows * 32
        short8 b0[2], b1[2];
        b0[0] = *(const short8*)(wb);
        if (en1) b0[1] = *(const short8*)(wb + 512);
        int aoff = aoff_base;

#pragma unroll 1
        for (int ks = 0; ks < 14; ks += 2) {
            const short* wk = wb + ks * 8192;
            b1[0] = *(const short8*)(wk + 8192);
            if (en1) b1[1] = *(const short8*)(wk + 8192 + 512);
            {
                short8 afr[4];
#pragma unroll
                for (int mf = 0; mf < 4; ++mf) {
                    afr[mf] = *(const short8*)(xl + aoff + mf * (16 * XROW));
                    acc[mf][0] = __builtin_amdgcn_mfma_f32_16x16x32_bf16(afr[mf], b0[0], acc[mf][0], 0, 0, 0);
                }
                if (en1) {
#pragma unroll
                    for (int mf = 0; mf < 4; ++mf)
                        acc[mf][1] = __builtin_amdgcn_mfma_f32_16x16x32_bf16(afr[mf], b0[1], acc[mf][1], 0, 0, 0);
                }
            }
            b0[0] = *(const short8*)(wk + 16384);
            if (en1) b0[1] = *(const short8*)(wk + 16384 + 512);
            {
                const int aoff1 = aoff + ((ks == 4) ? 40 : 32);  // tap wrap 4->5 inside pair
                short8 afr[4];
#pragma unroll
                for (int mf = 0; mf < 4; ++mf) {
                    afr[mf] = *(const short8*)(xl + aoff1 + mf * (16 * XROW));
                    acc[mf][0] = __builtin_amdgcn_mfma_f32_16x16x32_bf16(afr[mf], b1[0], acc[mf][0], 0, 0, 0);
                }
                if (en1) {
#pragma unroll
                    for (int mf = 0; mf < 4; ++mf)
                        acc[mf][1] = __builtin_amdgcn_mfma_f32_16x16x32_bf16(afr[mf], b1[1], acc[mf][1], 0, 0, 0);
                }
            }
            aoff += 64 + ((ks == 4 || ks == 8) ? 8 : 0);  // wraps 4->5 and 9->10
        }
        {   // tail ks=14 (in b0)
            short8 afr[4];
#pragma unroll
            for (int mf = 0; mf < 4; ++mf) {
                afr[mf] = *(const short8*)(xl + aoff + mf * (16 * XROW));
                acc[mf][0] = __builtin_amdgcn_mfma_f32_16x16x32_bf16(afr[mf], b0[0], acc[mf][0], 0, 0, 0);
            }
            if (en1) {
#pragma unroll
                for (int mf = 0; mf < 4; ++mf)
                    acc[mf][1] = __builtin_amdgcn_mfma_f32_16x16x32_bf16(afr[mf], b0[1], acc[mf][1], 0, 0, 0);
            }
        }
        // epilogue pass p: max over valid l, cross-lane reduce, stage to smax
#pragma unroll
        for (int nf = 0; nf < 2; ++nf) {
            float m = -1e30f;
#pragma unroll
            for (int mf = 0; mf < 4; ++mf) {
                int lbase = 64 * wm + 16 * mf + 4 * g;
#pragma unroll
                for (int r = 0; r < 4; ++r)
                    if (lbase + r < LLEN) m = fmaxf(m, acc[mf][nf][r]);
            }
            m = fmaxf(m, __shfl_xor(m, 16, 64));
            m = fmaxf(m, __shfl_xor(m, 32, 64));
            if (lane < 16) smax[wm * 256 + 64 * wn + 32 * p + 16 * nf + r16] = m;
        }
    }
    __syncthreads();
    for (int h = tid; h < HID; h += 512) {
        float v = fmaxf(smax[h], smax[256 + h]) + conv_b[h];
        enc[n * HID + h] = fmaxf(v, 0.f);
    }
}

// ---------------- bag self-attention + relation scores ----------------
__global__ void bag_kernel(const float* __restrict__ enc, const int* __restrict__ X_Rel,
                           const float* __restrict__ rel_W, const float* __restrict__ rel_b,
                           float* __restrict__ out) {
    __shared__ float bagv[BB][232];
    __shared__ float bag2[BB][232];
    __shared__ float att[BB][BB];
    __shared__ float relv[232];
    __shared__ float repv[232];
    __shared__ float sc[BB], sc2[BB];
    const int b = blockIdx.x, t = threadIdx.x;

    for (int i = t; i < BB * HID; i += 256) {
        int r = i / HID, d = i % HID;
        bagv[r][d] = enc[(b * BB + r) * HID + d];
    }
    __syncthreads();
    if (t < 64) {
        int i = t >> 3, j = t & 7;
        float acc = 0.f;
        for (int d = 0; d < HID; ++d) acc += bagv[i][d] * bagv[j][d];
        att[i][j] = acc * (1.0f / sqrtf(230.0f));
    }
    __syncthreads();
    if (t < 8) {
        float m = att[t][0];
        for (int j = 1; j < 8; ++j) m = fmaxf(m, att[t][j]);
        float e[8], s = 0.f;
        for (int j = 0; j < 8; ++j) { e[j] = expf(att[t][j] - m); s += e[j]; }
        float inv = 1.f / s;
        for (int j = 0; j < 8; ++j) att[t][j] = e[j] * inv;
    }
    __syncthreads();
    for (int i = t; i < BB * HID; i += 256) {
        int r = i / HID, d = i % HID;
        float acc = 0.f;
        for (int j = 0; j < 8; ++j) acc += att[r][j] * bagv[j][d];
        bag2[r][d] = acc;
    }
    if (t < HID) relv[t] = rel_W[X_Rel[b] * HID + t];
    __syncthreads();
    if (t < 8) {
        float acc = 0.f;
        for (int d = 0; d < HID; ++d) acc += bag2[t][d] * relv[d];
        sc[t] = acc;
    }
    __syncthreads();
    if (t < 8) {
        float m = sc[0];
        for (int j = 1; j < 8; ++j) m = fmaxf(m, sc[j]);
        sc2[t] = expf(sc[t] - m);
    }
    __syncthreads();
    if (t < HID) {
        float sum = 0.f;
        for (int j = 0; j < 8; ++j) sum += sc2[j];
        float acc = 0.f;
        for (int j = 0; j < 8; ++j) acc += sc2[j] * bag2[j][t];
        repv[t] = acc / sum;
    }
    __syncthreads();
    if (t < RELN) {
        float acc = rel_b[t];
        for (int d = 0; d < HID; ++d) acc += repv[d] * rel_W[t * HID + d];
        out[b * RELN + t] = acc;
    }
}

extern "C" void kernel_launch(void* const* d_in, const int* in_sizes, int n_in,
                              void* d_out, int out_size, void* d_ws, size_t ws_size,
                              hipStream_t stream) {
    const int* X       = (const int*)d_in[0];
    const int* XP1     = (const int*)d_in[1];
    const int* XP2     = (const int*)d_in[2];
    const int* E1      = (const int*)d_in[3];
    const int* E2      = (const int*)d_in[4];
    const int* Q       = (const int*)d_in[10];
    const int* X_Rel   = (const int*)d_in[11];
    const float* W_word = (const float*)d_in[12];
    const float* W_pos1 = (const float*)d_in[13];
    const float* W_pos2 = (const float*)d_in[14];
    const float* w_s   = (const float*)d_in[15];
    const float* b_s   = (const float*)d_in[16];
    const float* w_q   = (const float*)d_in[17];
    const float* b_q   = (const float*)d_in[18];
    const float* w_sq  = (const float*)d_in[19];
    const float* b_sq  = (const float*)d_in[20];
    const float* conv_W = (const float*)d_in[21];
    const float* conv_b = (const float*)d_in[22];
    const float* rel_W = (const float*)d_in[23];
    const float* rel_b = (const float*)d_in[24];
    float* out = (float*)d_out;

    char* ws = (char*)d_ws;
    float* q_ws = (float*)ws;                      // 512*8*50 f32
    float* enc  = q_ws + BAGS * QL * WD;           // 4096*230 f32
    short* wt2  = (short*)(enc + NSENT * HID);     // 15*256*32 bf16

    build_q_kernel<<<BAGS, 64, 0, stream>>>(Q, E1, E2, W_word, q_ws);
    pack_w_kernel<<<480, 256, 0, stream>>>(conv_W, wt2);

    const size_t lds_bytes =
        (size_t)XROWS * XROW * 2      // xl     40992
        + 64 * 32 * 2                 // qtb     4096
        + 136 * 8 * 2                 // abf     2176
        + 16 * 64 * 2                 // qwb     2048 (smax overlay)
        + LLEN * 8 * 2                // hm      1920 (smax/red overlay tail)
        + 4 * (LLEN + LLEN + 8);      // svv/bat/qsv = 992   -> total 52224
    sent_kernel<<<NSENT, 512, lds_bytes, stream>>>(
        X, XP1, XP2, W_word, W_pos1, W_pos2,
        w_s, b_s, w_q, b_q, w_sq, b_sq, conv_b, q_ws, wt2, enc);

    bag_kernel<<<BAGS, 256, 0, stream>>>(enc, X_Rel, rel_W, rel_b, out);
}